// Round 1
// baseline (718.710 us; speedup 1.0000x reference)
//
#include <hip/hip_runtime.h>
#include <hip/hip_bf16.h>

#define MAX_DET 300
#define NCAND 600           // MAX_DET * NUM_CLASSES
#define SCORE_THR 1e-3f
#define IOU_THR 0.7f
#define EPSF 1e-7f

// ws layout (floats):
//   [0, 256)        partial conv sums (4b * 16oc * 4chunks)
//   [256, 320)      fmean (4*16)
//   [320, 6320)     boxes5 (4*300*5)
//   [6320, 8720)    scores (4*300*2)

__global__ __launch_bounds__(256) void k_conv_pool(
    const float* __restrict__ x, const float* __restrict__ cw,
    const float* __restrict__ cb, float* __restrict__ partial) {
  const int blk = blockIdx.x;  // (b*16 + oc)*4 + chunk
  const int chunk = blk & 3;
  const int oc = (blk >> 2) & 15;
  const int b = blk >> 6;
  const int tid = threadIdx.x;

  float w[27];
#pragma unroll
  for (int i = 0; i < 27; ++i) w[i] = cw[oc * 27 + i];
  const float bias = cb[oc];
  const float* xb = x + b * 3 * 65536;

  float acc = 0.f;
  for (int p = chunk * 4096 + tid; p < (chunk + 1) * 4096; p += 256) {
    const int py = p >> 7, px = p & 127;
    const int oy0 = py * 2, ox0 = px * 2;
    float c0 = 0.f, c1 = 0.f, c2 = 0.f, c3 = 0.f;
#pragma unroll
    for (int ic = 0; ic < 3; ++ic) {
      const float* xc = xb + ic * 65536;
      float vin[4][4];
#pragma unroll
      for (int r = 0; r < 4; ++r) {
        const int yy = oy0 - 1 + r;
#pragma unroll
        for (int c = 0; c < 4; ++c) {
          const int xx = ox0 - 1 + c;
          float v = 0.f;
          if (yy >= 0 && yy < 256 && xx >= 0 && xx < 256) v = xc[yy * 256 + xx];
          vin[r][c] = v;
        }
      }
#pragma unroll
      for (int ky = 0; ky < 3; ++ky)
#pragma unroll
        for (int kx = 0; kx < 3; ++kx) {
          const float wv = w[ic * 9 + ky * 3 + kx];
          c0 += vin[ky][kx] * wv;
          c1 += vin[ky][kx + 1] * wv;
          c2 += vin[ky + 1][kx] * wv;
          c3 += vin[ky + 1][kx + 1] * wv;
        }
    }
    const float m = fmaxf(fmaxf(c0, c1), fmaxf(c2, c3));
    acc += fmaxf(m + bias, 0.f);  // relu(conv+bias) then 2x2 max == relu(max+bias)
  }
  __shared__ float red[256];
  red[tid] = acc;
  __syncthreads();
  for (int s = 128; s > 0; s >>= 1) {
    if (tid < s) red[tid] += red[tid + s];
    __syncthreads();
  }
  if (tid == 0) partial[blk] = red[0];
}

__global__ void k_reduce_fmean(const float* __restrict__ partial,
                               float* __restrict__ fmean) {
  const int t = threadIdx.x;  // 64 threads: b*16 + oc
  float s = 0.f;
  for (int k = 0; k < 4; ++k) s += partial[t * 4 + k];
  fmean[t] = s * (1.0f / 16384.0f);
}

__global__ void k_heads(const float* __restrict__ fmean,
                        const float* __restrict__ bw, const float* __restrict__ bb,
                        const float* __restrict__ cwm, const float* __restrict__ cbb,
                        const float* __restrict__ aw, const float* __restrict__ ab,
                        float* __restrict__ boxes5, float* __restrict__ scores) {
  const int t = blockIdx.x * blockDim.x + threadIdx.x;
  if (t >= 4 * MAX_DET) return;
  const int b = t / MAX_DET, det = t % MAX_DET;
  float f[16];
#pragma unroll
  for (int k = 0; k < 16; ++k) f[k] = fmean[b * 16 + k];

  float out5[5];
#pragma unroll
  for (int j = 0; j < 4; ++j) {
    const int o = det * 4 + j;
    float acc = bb[o];
#pragma unroll
    for (int k = 0; k < 16; ++k) acc += bw[o * 16 + k] * f[k];
    out5[j] = acc;
  }
  {
    float acc = ab[det];
#pragma unroll
    for (int k = 0; k < 16; ++k) acc += aw[det * 16 + k] * f[k];
    out5[4] = acc;
  }
  float l0, l1;
  {
    const int o = det * 2;
    float a0 = cbb[o], a1 = cbb[o + 1];
#pragma unroll
    for (int k = 0; k < 16; ++k) {
      a0 += cwm[o * 16 + k] * f[k];
      a1 += cwm[(o + 1) * 16 + k] * f[k];
    }
    l0 = a0; l1 = a1;
  }
  const float mx = fmaxf(l0, l1);
  const float e0 = expf(l0 - mx), e1 = expf(l1 - mx);
  const float inv = 1.f / (e0 + e1);

  float* bp = boxes5 + t * 5;
#pragma unroll
  for (int j = 0; j < 5; ++j) bp[j] = out5[j];
  scores[t * 2 + 0] = e0 * inv;
  scores[t * 2 + 1] = e1 * inv;
}

__global__ __launch_bounds__(256) void k_nms(const float* __restrict__ boxes5,
                                             const float* __restrict__ scores,
                                             float* __restrict__ out) {
  const int b = blockIdx.x;
  const int tid = threadIdx.x;

  __shared__ float sc[NCAND];          // candidate scores, cand order m = det*2+cls
  __shared__ int order[NCAND];         // sorted rank -> cand index
  __shared__ float sx[NCAND], sy[NCAND], sA[NCAND], sB[NCAND], sC[NCAND],
      sD[NCAND], ss[NCAND];            // gaussian params + score, sorted order
  __shared__ unsigned long long mask[NCAND * 10];  // suppression bitmask rows
  __shared__ unsigned long long keepw[10];

  // 1. candidate scores
  for (int m = tid; m < NCAND; m += 256) sc[m] = scores[b * NCAND + m];
  __syncthreads();

  // 2. stable descending rank (argsort(-s), ties by index)
  for (int i = tid; i < NCAND; i += 256) {
    const float si = sc[i];
    int r = 0;
    for (int j = 0; j < NCAND; ++j) {
      const float sj = sc[j];
      r += (sj > si) || (sj == si && j < i);
    }
    order[r] = i;
  }
  __syncthreads();

  // 3. gaussian params in sorted order
  for (int r = tid; r < NCAND; r += 256) {
    const int i = order[r];
    const float* bp = boxes5 + (b * MAX_DET + (i >> 1)) * 5;
    const float cx = bp[0], cy = bp[1], w = bp[2], h = bp[3], t = bp[4];
    const float ct = cosf(t), st = sinf(t);
    const float w2 = w * w * (1.f / 12.f), h2 = h * h * (1.f / 12.f);
    const float a = w2 * ct * ct + h2 * st * st;
    const float bb = w2 * st * st + h2 * ct * ct;
    const float c = (w2 - h2) * ct * st;
    sx[r] = cx; sy[r] = cy; sA[r] = a; sB[r] = bb; sC[r] = c;
    sD[r] = fmaxf(a * bb - c * c, 0.f);
    ss[r] = sc[i];
  }
  __syncthreads();

  // 4. suppression matrix: bit j of row i set iff j>i, same label, iou>thr
  for (int task = tid; task < NCAND * 10; task += 256) {
    const int row = task / 10, word = task % 10;
    const int lab_i = order[row] & 1;
    const float x1 = sx[row], y1 = sy[row], a1 = sA[row], b1 = sB[row],
                c1 = sC[row], d1 = sD[row];
    unsigned long long mword = 0ULL;
    const int jbase = word * 64;
    for (int bit = 0; bit < 64; ++bit) {
      const int j = jbase + bit;
      if (j <= row || j >= NCAND) continue;
      if ((order[j] & 1) != lab_i) continue;
      const float as = a1 + sA[j], bs = b1 + sB[j], cs = c1 + sC[j];
      const float dxx = sx[j] - x1;   // x2 - x1
      const float dyy = y1 - sy[j];   // y1 - y2
      const float denom = as * bs - cs * cs + EPSF;
      const float rden = 1.f / denom;
      const float t1v = 0.25f * (as * dyy * dyy + bs * dxx * dxx) * rden;
      const float t2v = 0.5f * (cs * dxx * dyy) * rden;
      const float t3v = 0.5f * logf(denom / (4.f * sqrtf(d1 * sD[j]) + EPSF) + EPSF);
      float bd = t1v + t2v + t3v;
      bd = fminf(fmaxf(bd, EPSF), 100.f);
      const float hd = sqrtf(1.f - expf(-bd) + EPSF);
      if (1.f - hd > IOU_THR) mword |= (1ULL << bit);
    }
    mask[task] = mword;
  }
  __syncthreads();

  // 5. sequential greedy scan — single wave, keep mask in wave registers
  if (tid < 64) {
    unsigned long long keep = 0ULL;
    if (tid < 10) {
      for (int bit = 0; bit < 64; ++bit) {
        const int j = tid * 64 + bit;
        if (j < NCAND && ss[j] > SCORE_THR) keep |= (1ULL << bit);
      }
    }
    unsigned long long mrow = (tid < 10) ? mask[tid] : 0ULL;
    for (int i = 0; i < NCAND; ++i) {
      unsigned long long nrow = 0ULL;
      if (i + 1 < NCAND && tid < 10) nrow = mask[(i + 1) * 10 + tid];  // prefetch
      const unsigned long long kw = __shfl(keep, i >> 6, 64);
      if ((kw >> (i & 63)) & 1ULL) keep &= ~mrow;
      mrow = nrow;
    }
    if (tid < 10) keepw[tid] = keep;
  }
  __syncthreads();

  // 6. zero this batch's output slice, then scatter kept detections
  for (int k = tid; k < MAX_DET * 5; k += 256) out[b * MAX_DET * 5 + k] = 0.f;
  for (int k = tid; k < MAX_DET; k += 256) {
    out[6000 + b * MAX_DET + k] = 0.f;   // scores
    out[7200 + b * MAX_DET + k] = 0.f;   // labels
  }
  __syncthreads();

  for (int r = tid; r < NCAND; r += 256) {
    const int w = r >> 6, bitp = r & 63;
    if ((keepw[w] >> bitp) & 1ULL) {
      int pos = 0;
      for (int ww = 0; ww < w; ++ww) pos += __popcll(keepw[ww]);
      pos += __popcll(keepw[w] & ((1ULL << bitp) - 1ULL));
      if (pos < MAX_DET) {
        const int i = order[r];
        const float* bp = boxes5 + (b * MAX_DET + (i >> 1)) * 5;
        float* ob = out + (b * MAX_DET + pos) * 5;
        ob[0] = bp[0]; ob[1] = bp[1]; ob[2] = bp[2]; ob[3] = bp[3]; ob[4] = bp[4];
        out[6000 + b * MAX_DET + pos] = ss[r];
        out[7200 + b * MAX_DET + pos] = (float)(i & 1);
      }
    }
  }
  if (tid == 0) {
    int total = 0;
    for (int ww = 0; ww < 10; ++ww) total += __popcll(keepw[ww]);
    if (total > MAX_DET) total = MAX_DET;
    out[8400 + b] = (float)total;
  }
}

extern "C" void kernel_launch(void* const* d_in, const int* in_sizes, int n_in,
                              void* d_out, int out_size, void* d_ws, size_t ws_size,
                              hipStream_t stream) {
  const float* x      = (const float*)d_in[0];
  const float* conv_w = (const float*)d_in[1];
  const float* conv_b = (const float*)d_in[2];
  const float* bbox_w = (const float*)d_in[3];
  const float* bbox_b = (const float*)d_in[4];
  const float* cls_w  = (const float*)d_in[5];
  const float* cls_b  = (const float*)d_in[6];
  const float* ang_w  = (const float*)d_in[7];
  const float* ang_b  = (const float*)d_in[8];
  float* out = (float*)d_out;
  float* ws = (float*)d_ws;

  float* partial = ws;          // 256
  float* fmean   = ws + 256;    // 64
  float* boxes5  = ws + 320;    // 6000
  float* scores  = ws + 6320;   // 2400

  k_conv_pool<<<256, 256, 0, stream>>>(x, conv_w, conv_b, partial);
  k_reduce_fmean<<<1, 64, 0, stream>>>(partial, fmean);
  k_heads<<<5, 256, 0, stream>>>(fmean, bbox_w, bbox_b, cls_w, cls_b,
                                 ang_w, ang_b, boxes5, scores);
  k_nms<<<4, 256, 0, stream>>>(boxes5, scores, out);
}

// Round 2
// 173.203 us; speedup vs baseline: 4.1495x; 4.1495x over previous
//
#include <hip/hip_runtime.h>
#include <hip/hip_bf16.h>

#define MAX_DET 300
#define NCAND 600           // MAX_DET * NUM_CLASSES
#define NPAD 640            // padded candidate stride
#define SCORE_THR 1e-3f
#define IOU_THR 0.7f
#define EPSF 1e-7f

// ws layout (floats):
//   [0, 256)         partial conv sums (4b * 16oc * 4chunks)
//   [256, 320)       fmean (4*16)
//   [320, 6320)      boxes5 (4*300*5)
//   [6320, 8720)     scores (4*300*2)
//   [8720, 26640)    sorted params: 4 batches x 7 arrays x 640  (x,y,A,B,C,D,s)
//   [26640, 29200)   order (int), 4 x 640
//   [29200, 77200)   mask (u64), 4 x 600 x 10   (192 KB)

__global__ __launch_bounds__(256) void k_conv_pool(
    const float* __restrict__ x, const float* __restrict__ cw,
    const float* __restrict__ cb, float* __restrict__ partial) {
  const int blk = blockIdx.x;  // (b*16 + oc)*4 + chunk
  const int chunk = blk & 3;
  const int oc = (blk >> 2) & 15;
  const int b = blk >> 6;
  const int tid = threadIdx.x;

  float w[27];
#pragma unroll
  for (int i = 0; i < 27; ++i) w[i] = cw[oc * 27 + i];
  const float bias = cb[oc];
  const float* xb = x + b * 3 * 65536;

  float acc = 0.f;
  for (int p = chunk * 4096 + tid; p < (chunk + 1) * 4096; p += 256) {
    const int py = p >> 7, px = p & 127;
    const int oy0 = py * 2, ox0 = px * 2;
    float c0 = 0.f, c1 = 0.f, c2 = 0.f, c3 = 0.f;
#pragma unroll
    for (int ic = 0; ic < 3; ++ic) {
      const float* xc = xb + ic * 65536;
      float vin[4][4];
#pragma unroll
      for (int r = 0; r < 4; ++r) {
        const int yy = oy0 - 1 + r;
#pragma unroll
        for (int c = 0; c < 4; ++c) {
          const int xx = ox0 - 1 + c;
          float v = 0.f;
          if (yy >= 0 && yy < 256 && xx >= 0 && xx < 256) v = xc[yy * 256 + xx];
          vin[r][c] = v;
        }
      }
#pragma unroll
      for (int ky = 0; ky < 3; ++ky)
#pragma unroll
        for (int kx = 0; kx < 3; ++kx) {
          const float wv = w[ic * 9 + ky * 3 + kx];
          c0 += vin[ky][kx] * wv;
          c1 += vin[ky][kx + 1] * wv;
          c2 += vin[ky + 1][kx] * wv;
          c3 += vin[ky + 1][kx + 1] * wv;
        }
    }
    const float m = fmaxf(fmaxf(c0, c1), fmaxf(c2, c3));
    acc += fmaxf(m + bias, 0.f);  // relu(conv+bias) then 2x2 max == relu(max+bias)
  }
  __shared__ float red[256];
  red[tid] = acc;
  __syncthreads();
  for (int s = 128; s > 0; s >>= 1) {
    if (tid < s) red[tid] += red[tid + s];
    __syncthreads();
  }
  if (tid == 0) partial[blk] = red[0];
}

__global__ void k_reduce_fmean(const float* __restrict__ partial,
                               float* __restrict__ fmean) {
  const int t = threadIdx.x;  // 64 threads: b*16 + oc
  float s = 0.f;
  for (int k = 0; k < 4; ++k) s += partial[t * 4 + k];
  fmean[t] = s * (1.0f / 16384.0f);
}

__global__ void k_heads(const float* __restrict__ fmean,
                        const float* __restrict__ bw, const float* __restrict__ bb,
                        const float* __restrict__ cwm, const float* __restrict__ cbb,
                        const float* __restrict__ aw, const float* __restrict__ ab,
                        float* __restrict__ boxes5, float* __restrict__ scores) {
  const int t = blockIdx.x * blockDim.x + threadIdx.x;
  if (t >= 4 * MAX_DET) return;
  const int b = t / MAX_DET, det = t % MAX_DET;
  float f[16];
#pragma unroll
  for (int k = 0; k < 16; ++k) f[k] = fmean[b * 16 + k];

  float out5[5];
#pragma unroll
  for (int j = 0; j < 4; ++j) {
    const int o = det * 4 + j;
    float acc = bb[o];
#pragma unroll
    for (int k = 0; k < 16; ++k) acc += bw[o * 16 + k] * f[k];
    out5[j] = acc;
  }
  {
    float acc = ab[det];
#pragma unroll
    for (int k = 0; k < 16; ++k) acc += aw[det * 16 + k] * f[k];
    out5[4] = acc;
  }
  float l0, l1;
  {
    const int o = det * 2;
    float a0 = cbb[o], a1 = cbb[o + 1];
#pragma unroll
    for (int k = 0; k < 16; ++k) {
      a0 += cwm[o * 16 + k] * f[k];
      a1 += cwm[(o + 1) * 16 + k] * f[k];
    }
    l0 = a0; l1 = a1;
  }
  const float mx = fmaxf(l0, l1);
  const float e0 = expf(l0 - mx), e1 = expf(l1 - mx);
  const float inv = 1.f / (e0 + e1);

  float* bp = boxes5 + t * 5;
#pragma unroll
  for (int j = 0; j < 5; ++j) bp[j] = out5[j];
  scores[t * 2 + 0] = e0 * inv;
  scores[t * 2 + 1] = e1 * inv;
}

// Sort candidates by score (stable desc) and emit sorted gaussian params.
__global__ __launch_bounds__(256) void k_prep(
    const float* __restrict__ boxes5, const float* __restrict__ scores,
    float* __restrict__ sparams, int* __restrict__ order_g) {
  const int b = blockIdx.x;
  const int tid = threadIdx.x;
  __shared__ float sc[NCAND];
  __shared__ int order[NCAND];

  for (int m = tid; m < NCAND; m += 256) sc[m] = scores[b * NCAND + m];
  __syncthreads();

  for (int i = tid; i < NCAND; i += 256) {
    const float si = sc[i];
    int r = 0;
    for (int j = 0; j < NCAND; ++j) {
      const float sj = sc[j];
      r += (sj > si) || (sj == si && j < i);
    }
    order[r] = i;
  }
  __syncthreads();

  float* P = sparams + b * 7 * NPAD;
  for (int r = tid; r < NCAND; r += 256) {
    const int i = order[r];
    order_g[b * NPAD + r] = i;
    const float* bp = boxes5 + (b * MAX_DET + (i >> 1)) * 5;
    const float cx = bp[0], cy = bp[1], w = bp[2], h = bp[3], t = bp[4];
    const float ct = cosf(t), st = sinf(t);
    const float w2 = w * w * (1.f / 12.f), h2 = h * h * (1.f / 12.f);
    const float a = w2 * ct * ct + h2 * st * st;
    const float bb = w2 * st * st + h2 * ct * ct;
    const float c = (w2 - h2) * ct * st;
    P[0 * NPAD + r] = cx;
    P[1 * NPAD + r] = cy;
    P[2 * NPAD + r] = a;
    P[3 * NPAD + r] = bb;
    P[4 * NPAD + r] = c;
    P[5 * NPAD + r] = fmaxf(a * bb - c * c, 0.f);
    P[6 * NPAD + r] = sc[i];
  }
}

// One wave per sorted row; 10 ballots build the 600-bit suppression row.
__global__ __launch_bounds__(256) void k_mask(
    const float* __restrict__ sparams, const int* __restrict__ order_g,
    unsigned long long* __restrict__ mask) {
  const int wid = threadIdx.x >> 6, lane = threadIdx.x & 63;
  const int g = blockIdx.x * 4 + wid;  // 0 .. 2399
  const int b = g / NCAND, i = g % NCAND;

  const float* P = sparams + b * 7 * NPAD;
  const int* og = order_g + b * NPAD;
  const float x1 = P[i], y1 = P[NPAD + i], a1 = P[2 * NPAD + i],
              b1 = P[3 * NPAD + i], c1 = P[4 * NPAD + i], d1 = P[5 * NPAD + i];
  const int li = og[i] & 1;

#pragma unroll
  for (int w = 0; w < 10; ++w) {
    const int j = w * 64 + lane;
    const int jc = j < NCAND ? j : NCAND - 1;
    const float x2 = P[jc], y2 = P[NPAD + jc], a2 = P[2 * NPAD + jc],
                b2 = P[3 * NPAD + jc], c2 = P[4 * NPAD + jc],
                d2 = P[5 * NPAD + jc];
    const float as = a1 + a2, bs = b1 + b2, cs = c1 + c2;
    const float dxx = x2 - x1, dyy = y1 - y2;
    const float denom = as * bs - cs * cs + EPSF;
    const float rden = 1.f / denom;
    const float t1v = 0.25f * (as * dyy * dyy + bs * dxx * dxx) * rden;
    const float t2v = 0.5f * (cs * dxx * dyy) * rden;
    const float t3v = 0.5f * logf(denom / (4.f * sqrtf(d1 * d2) + EPSF) + EPSF);
    float bd = t1v + t2v + t3v;
    bd = fminf(fmaxf(bd, EPSF), 100.f);
    const float hd = sqrtf(1.f - expf(-bd) + EPSF);
    const bool cond = (j > i) && (j < NCAND) && ((og[jc] & 1) == li) &&
                      ((1.f - hd) > IOU_THR);
    const unsigned long long mw = __ballot(cond);
    if (lane == 0) mask[(b * NCAND + i) * 10 + w] = mw;
  }
}

// Sequential greedy scan + output scatter. One wave per batch.
__global__ __launch_bounds__(64) void k_scan(
    const float* __restrict__ boxes5, const float* __restrict__ sparams,
    const int* __restrict__ order_g, const unsigned long long* __restrict__ mask,
    float* __restrict__ out) {
  const int b = blockIdx.x;
  const int tid = threadIdx.x;

  __shared__ unsigned long long m[NCAND * 10];
  __shared__ float ssc[NCAND];
  __shared__ unsigned long long keepw[10];

  const unsigned long long* mg = mask + b * NCAND * 10;
  for (int k = tid; k < NCAND * 10; k += 64) m[k] = mg[k];
  const float* P = sparams + b * 7 * NPAD;
  for (int k = tid; k < NCAND; k += 64) ssc[k] = P[6 * NPAD + k];
  __syncthreads();

  {
    unsigned long long keep = 0ULL;
    if (tid < 10) {
      for (int bit = 0; bit < 64; ++bit) {
        const int j = tid * 64 + bit;
        if (j < NCAND && ssc[j] > SCORE_THR) keep |= (1ULL << bit);
      }
    }
    unsigned long long mrow = (tid < 10) ? m[tid] : 0ULL;
    for (int i = 0; i < NCAND; ++i) {
      unsigned long long nrow = 0ULL;
      if (i + 1 < NCAND && tid < 10) nrow = m[(i + 1) * 10 + tid];  // prefetch
      const unsigned long long kw = __shfl(keep, i >> 6, 64);
      if ((kw >> (i & 63)) & 1ULL) keep &= ~mrow;
      mrow = nrow;
    }
    if (tid < 10) keepw[tid] = keep;
  }
  __syncthreads();

  for (int k = tid; k < MAX_DET * 5; k += 64) out[b * MAX_DET * 5 + k] = 0.f;
  for (int k = tid; k < MAX_DET; k += 64) {
    out[6000 + b * MAX_DET + k] = 0.f;   // scores
    out[7200 + b * MAX_DET + k] = 0.f;   // labels
  }
  __syncthreads();

  const int* og = order_g + b * NPAD;
  for (int r = tid; r < NCAND; r += 64) {
    const int w = r >> 6, bitp = r & 63;
    if ((keepw[w] >> bitp) & 1ULL) {
      int pos = 0;
      for (int ww = 0; ww < w; ++ww) pos += __popcll(keepw[ww]);
      pos += __popcll(keepw[w] & ((1ULL << bitp) - 1ULL));
      if (pos < MAX_DET) {
        const int i = og[r];
        const float* bp = boxes5 + (b * MAX_DET + (i >> 1)) * 5;
        float* ob = out + (b * MAX_DET + pos) * 5;
        ob[0] = bp[0]; ob[1] = bp[1]; ob[2] = bp[2]; ob[3] = bp[3]; ob[4] = bp[4];
        out[6000 + b * MAX_DET + pos] = ssc[r];
        out[7200 + b * MAX_DET + pos] = (float)(i & 1);
      }
    }
  }
  if (tid == 0) {
    int total = 0;
    for (int ww = 0; ww < 10; ++ww) total += __popcll(keepw[ww]);
    if (total > MAX_DET) total = MAX_DET;
    out[8400 + b] = (float)total;
  }
}

extern "C" void kernel_launch(void* const* d_in, const int* in_sizes, int n_in,
                              void* d_out, int out_size, void* d_ws, size_t ws_size,
                              hipStream_t stream) {
  const float* x      = (const float*)d_in[0];
  const float* conv_w = (const float*)d_in[1];
  const float* conv_b = (const float*)d_in[2];
  const float* bbox_w = (const float*)d_in[3];
  const float* bbox_b = (const float*)d_in[4];
  const float* cls_w  = (const float*)d_in[5];
  const float* cls_b  = (const float*)d_in[6];
  const float* ang_w  = (const float*)d_in[7];
  const float* ang_b  = (const float*)d_in[8];
  float* out = (float*)d_out;
  float* ws = (float*)d_ws;

  float* partial = ws;            // 256
  float* fmean   = ws + 256;      // 64
  float* boxes5  = ws + 320;      // 6000
  float* scores  = ws + 6320;     // 2400
  float* sparams = ws + 8720;     // 4*7*640 = 17920
  int*   order_g = (int*)(ws + 26640);                       // 4*640
  unsigned long long* mask = (unsigned long long*)(ws + 29200);  // 4*600*10 u64

  k_conv_pool<<<256, 256, 0, stream>>>(x, conv_w, conv_b, partial);
  k_reduce_fmean<<<1, 64, 0, stream>>>(partial, fmean);
  k_heads<<<5, 256, 0, stream>>>(fmean, bbox_w, bbox_b, cls_w, cls_b,
                                 ang_w, ang_b, boxes5, scores);
  k_prep<<<4, 256, 0, stream>>>(boxes5, scores, sparams, order_g);
  k_mask<<<600, 256, 0, stream>>>(sparams, order_g, mask);
  k_scan<<<4, 64, 0, stream>>>(boxes5, sparams, order_g, mask, out);
}

// Round 5
// 102.808 us; speedup vs baseline: 6.9908x; 1.6847x over previous
//
#include <hip/hip_runtime.h>
#include <hip/hip_bf16.h>

#define MAX_DET 300
#define NCAND 600           // MAX_DET * NUM_CLASSES
#define NPAD 640            // padded candidate stride
#define SCORE_THR 1e-3f
#define IOU_THR 0.7f
#define EPSF 1e-7f

// ws layout (floats):
//   [0, 256)         partial conv sums (4b * 16oc * 4chunks)
//   [320, 6320)      boxes5 (4*300*5)
//   [6320, 8720)     scores (4*300*2)
//   [8720, 26640)    sorted params: 4 batches x 7 arrays x 640  (x,y,A,B,C,D,s)
//   [26640, 29200)   order (int), 4 x 640
//   [29200, 77200)   mask (u64), 4 x 600 x 10

static __device__ inline unsigned long long readlane64(unsigned long long v, int l) {
  unsigned int lo = (unsigned int)v;
  unsigned int hi = (unsigned int)(v >> 32);
  unsigned int slo = (unsigned int)__builtin_amdgcn_readlane((int)lo, l);
  unsigned int shi = (unsigned int)__builtin_amdgcn_readlane((int)hi, l);
  return ((unsigned long long)shi << 32) | (unsigned long long)slo;
}

__global__ __launch_bounds__(256) void k_conv_pool(
    const float* __restrict__ x, const float* __restrict__ cw,
    const float* __restrict__ cb, float* __restrict__ partial) {
  const int blk = blockIdx.x;  // (b*16 + oc)*4 + chunk
  const int chunk = blk & 3;
  const int oc = (blk >> 2) & 15;
  const int b = blk >> 6;
  const int tid = threadIdx.x;

  float w[27];
#pragma unroll
  for (int i = 0; i < 27; ++i) w[i] = cw[oc * 27 + i];
  const float bias = cb[oc];
  const float* xb = x + b * 3 * 65536;

  float acc = 0.f;
  for (int p = chunk * 4096 + tid; p < (chunk + 1) * 4096; p += 256) {
    const int py = p >> 7, px = p & 127;
    const int oy0 = py * 2, ox0 = px * 2;
    float c0 = 0.f, c1 = 0.f, c2 = 0.f, c3 = 0.f;
#pragma unroll
    for (int ic = 0; ic < 3; ++ic) {
      const float* xc = xb + ic * 65536;
      float vin[4][4];
#pragma unroll
      for (int r = 0; r < 4; ++r) {
        const int yy = oy0 - 1 + r;
#pragma unroll
        for (int c = 0; c < 4; ++c) {
          const int xx = ox0 - 1 + c;
          float v = 0.f;
          if (yy >= 0 && yy < 256 && xx >= 0 && xx < 256) v = xc[yy * 256 + xx];
          vin[r][c] = v;
        }
      }
#pragma unroll
      for (int ky = 0; ky < 3; ++ky)
#pragma unroll
        for (int kx = 0; kx < 3; ++kx) {
          const float wv = w[ic * 9 + ky * 3 + kx];
          c0 += vin[ky][kx] * wv;
          c1 += vin[ky][kx + 1] * wv;
          c2 += vin[ky + 1][kx] * wv;
          c3 += vin[ky + 1][kx + 1] * wv;
        }
    }
    const float m = fmaxf(fmaxf(c0, c1), fmaxf(c2, c3));
    acc += fmaxf(m + bias, 0.f);
  }
  __shared__ float red[256];
  red[tid] = acc;
  __syncthreads();
  for (int s = 128; s > 0; s >>= 1) {
    if (tid < s) red[tid] += red[tid + s];
    __syncthreads();
  }
  if (tid == 0) partial[blk] = red[0];
}

__global__ __launch_bounds__(256) void k_heads(
    const float* __restrict__ partial,
    const float* __restrict__ bw, const float* __restrict__ bb,
    const float* __restrict__ cwm, const float* __restrict__ cbb,
    const float* __restrict__ aw, const float* __restrict__ ab,
    float* __restrict__ boxes5, float* __restrict__ scores) {
  __shared__ float fm[64];
  if (threadIdx.x < 64) {
    float s = 0.f;
    for (int k = 0; k < 4; ++k) s += partial[threadIdx.x * 4 + k];
    fm[threadIdx.x] = s * (1.0f / 16384.0f);
  }
  __syncthreads();

  const int t = blockIdx.x * blockDim.x + threadIdx.x;
  if (t >= 4 * MAX_DET) return;
  const int b = t / MAX_DET, det = t % MAX_DET;
  float f[16];
#pragma unroll
  for (int k = 0; k < 16; ++k) f[k] = fm[b * 16 + k];

  float out5[5];
#pragma unroll
  for (int j = 0; j < 4; ++j) {
    const int o = det * 4 + j;
    float acc = bb[o];
#pragma unroll
    for (int k = 0; k < 16; ++k) acc += bw[o * 16 + k] * f[k];
    out5[j] = acc;
  }
  {
    float acc = ab[det];
#pragma unroll
    for (int k = 0; k < 16; ++k) acc += aw[det * 16 + k] * f[k];
    out5[4] = acc;
  }
  float l0, l1;
  {
    const int o = det * 2;
    float a0 = cbb[o], a1 = cbb[o + 1];
#pragma unroll
    for (int k = 0; k < 16; ++k) {
      a0 += cwm[o * 16 + k] * f[k];
      a1 += cwm[(o + 1) * 16 + k] * f[k];
    }
    l0 = a0; l1 = a1;
  }
  const float mx = fmaxf(l0, l1);
  const float e0 = expf(l0 - mx), e1 = expf(l1 - mx);
  const float inv = 1.f / (e0 + e1);

  float* bp = boxes5 + t * 5;
#pragma unroll
  for (int j = 0; j < 5; ++j) bp[j] = out5[j];
  scores[t * 2 + 0] = e0 * inv;
  scores[t * 2 + 1] = e1 * inv;
}

// Sort candidates by score (stable desc) and emit sorted gaussian params.
__global__ __launch_bounds__(256) void k_prep(
    const float* __restrict__ boxes5, const float* __restrict__ scores,
    float* __restrict__ sparams, int* __restrict__ order_g) {
  const int b = blockIdx.x;
  const int tid = threadIdx.x;
  __shared__ float sc[NCAND];
  __shared__ int order[NCAND];

  for (int m = tid; m < NCAND; m += 256) sc[m] = scores[b * NCAND + m];
  __syncthreads();

  for (int i = tid; i < NCAND; i += 256) {
    const float si = sc[i];
    int r = 0;
    for (int j = 0; j < NCAND; ++j) {
      const float sj = sc[j];
      r += (sj > si) || (sj == si && j < i);
    }
    order[r] = i;
  }
  __syncthreads();

  float* P = sparams + b * 7 * NPAD;
  for (int r = tid; r < NCAND; r += 256) {
    const int i = order[r];
    order_g[b * NPAD + r] = i;
    const float* bp = boxes5 + (b * MAX_DET + (i >> 1)) * 5;
    const float cx = bp[0], cy = bp[1], w = bp[2], h = bp[3], t = bp[4];
    const float ct = cosf(t), st = sinf(t);
    const float w2 = w * w * (1.f / 12.f), h2 = h * h * (1.f / 12.f);
    const float a = w2 * ct * ct + h2 * st * st;
    const float bb = w2 * st * st + h2 * ct * ct;
    const float c = (w2 - h2) * ct * st;
    P[0 * NPAD + r] = cx;
    P[1 * NPAD + r] = cy;
    P[2 * NPAD + r] = a;
    P[3 * NPAD + r] = bb;
    P[4 * NPAD + r] = c;
    P[5 * NPAD + r] = fmaxf(a * bb - c * c, 0.f);
    P[6 * NPAD + r] = sc[i];
  }
}

// One wave per sorted row; 10 ballots build the 600-bit suppression row.
__global__ __launch_bounds__(256) void k_mask(
    const float* __restrict__ sparams, const int* __restrict__ order_g,
    unsigned long long* __restrict__ mask) {
  const int wid = threadIdx.x >> 6, lane = threadIdx.x & 63;
  const int g = blockIdx.x * 4 + wid;  // 0 .. 2399
  const int b = g / NCAND, i = g % NCAND;

  const float* P = sparams + b * 7 * NPAD;
  const int* og = order_g + b * NPAD;
  const float x1 = P[i], y1 = P[NPAD + i], a1 = P[2 * NPAD + i],
              b1 = P[3 * NPAD + i], c1 = P[4 * NPAD + i], d1 = P[5 * NPAD + i];
  const int li = og[i] & 1;

#pragma unroll
  for (int w = 0; w < 10; ++w) {
    const int j = w * 64 + lane;
    const int jc = j < NCAND ? j : NCAND - 1;
    const float x2 = P[jc], y2 = P[NPAD + jc], a2 = P[2 * NPAD + jc],
                b2 = P[3 * NPAD + jc], c2 = P[4 * NPAD + jc],
                d2 = P[5 * NPAD + jc];
    const float as = a1 + a2, bs = b1 + b2, cs = c1 + c2;
    const float dxx = x2 - x1, dyy = y1 - y2;
    const float denom = as * bs - cs * cs + EPSF;
    const float rden = 1.f / denom;
    const float t1v = 0.25f * (as * dyy * dyy + bs * dxx * dxx) * rden;
    const float t2v = 0.5f * (cs * dxx * dyy) * rden;
    const float t3v = 0.5f * logf(denom / (4.f * sqrtf(d1 * d2) + EPSF) + EPSF);
    float bd = t1v + t2v + t3v;
    bd = fminf(fmaxf(bd, EPSF), 100.f);
    const float hd = sqrtf(1.f - expf(-bd) + EPSF);
    const bool cond = (j > i) && (j < NCAND) && ((og[jc] & 1) == li) &&
                      ((1.f - hd) > IOU_THR);
    const unsigned long long mw = __ballot(cond);
    if (lane == 0) mask[(b * NCAND + i) * 10 + w] = mw;
  }
}

// Scalar greedy scan over nonzero-mask rows only + output scatter. 256 threads.
__global__ __launch_bounds__(256) void k_scan(
    const float* __restrict__ boxes5, const float* __restrict__ sparams,
    const int* __restrict__ order_g, const unsigned long long* __restrict__ mask,
    float* __restrict__ out) {
  const int b = blockIdx.x;
  const int tid = threadIdx.x;
  const int wid = tid >> 6, lane = tid & 63;

  __shared__ unsigned long long m[NCAND * 10];
  __shared__ float ssc[NCAND];
  __shared__ unsigned long long keepw[10];
  __shared__ unsigned long long validbm[10];
  __shared__ unsigned long long nzbm[10];

  // coalesced global -> LDS mask copy (256 threads)
  const unsigned long long* mg = mask + b * NCAND * 10;
  for (int k = tid; k < NCAND * 10; k += 256) m[k] = mg[k];
  const float* P = sparams + b * 7 * NPAD;
  for (int k = tid; k < NCAND; k += 256) ssc[k] = P[6 * NPAD + k];
  __syncthreads();

  // ballot-built bitmaps: valid (score>thr) and nonzero-mask rows
#pragma unroll
  for (int it = 0; it < 3; ++it) {
    const int g = wid + 4 * it;  // word index 0..11
    if (g < 10) {
      const int r = g * 64 + lane;
      bool valid = false;
      unsigned long long nzr = 0ULL;
      if (r < NCAND) {
        valid = ssc[r] > SCORE_THR;
        for (int k = 0; k < 10; ++k) nzr |= m[r * 10 + k];
      }
      const unsigned long long vb = __ballot(valid);
      const unsigned long long nb = __ballot(nzr != 0ULL);
      if (lane == 0) { validbm[g] = vb; nzbm[g] = nb; }
    }
  }
  __syncthreads();

  // wave-0 scalar greedy scan: visit only rows with nonzero suppression mask
  if (tid < 64) {
    unsigned long long keep = (lane < 10) ? validbm[lane] : 0ULL;
    const unsigned long long nzv = (lane < 10) ? nzbm[lane] : 0ULL;
#pragma unroll
    for (int w = 0; w < 10; ++w) {
      unsigned long long nzs = readlane64(nzv, w);
      unsigned long long ks = readlane64(keep, w);  // scalar cache of keep word w
      while (nzs) {
        const int bit = __builtin_ctzll(nzs);
        nzs &= nzs - 1ULL;
        if ((ks >> bit) & 1ULL) {
          const int i = w * 64 + bit;
          unsigned long long row = 0ULL;
          if (lane < 10) row = m[i * 10 + lane];
          keep &= ~row;
          ks &= ~readlane64(row, w);
        }
      }
    }
    if (lane < 10) keepw[lane] = keep;
  }
  __syncthreads();

  for (int k = tid; k < MAX_DET * 5; k += 256) out[b * MAX_DET * 5 + k] = 0.f;
  for (int k = tid; k < MAX_DET; k += 256) {
    out[6000 + b * MAX_DET + k] = 0.f;   // scores
    out[7200 + b * MAX_DET + k] = 0.f;   // labels
  }
  __syncthreads();

  const int* og = order_g + b * NPAD;
  for (int r = tid; r < NCAND; r += 256) {
    const int w = r >> 6, bitp = r & 63;
    if ((keepw[w] >> bitp) & 1ULL) {
      int pos = 0;
      for (int ww = 0; ww < w; ++ww) pos += __popcll(keepw[ww]);
      pos += __popcll(keepw[w] & ((1ULL << bitp) - 1ULL));
      if (pos < MAX_DET) {
        const int i = og[r];
        const float* bp = boxes5 + (b * MAX_DET + (i >> 1)) * 5;
        float* ob = out + (b * MAX_DET + pos) * 5;
        ob[0] = bp[0]; ob[1] = bp[1]; ob[2] = bp[2]; ob[3] = bp[3]; ob[4] = bp[4];
        out[6000 + b * MAX_DET + pos] = ssc[r];
        out[7200 + b * MAX_DET + pos] = (float)(i & 1);
      }
    }
  }
  if (tid == 0) {
    int total = 0;
    for (int ww = 0; ww < 10; ++ww) total += __popcll(keepw[ww]);
    if (total > MAX_DET) total = MAX_DET;
    out[8400 + b] = (float)total;
  }
}

extern "C" void kernel_launch(void* const* d_in, const int* in_sizes, int n_in,
                              void* d_out, int out_size, void* d_ws, size_t ws_size,
                              hipStream_t stream) {
  const float* x      = (const float*)d_in[0];
  const float* conv_w = (const float*)d_in[1];
  const float* conv_b = (const float*)d_in[2];
  const float* bbox_w = (const float*)d_in[3];
  const float* bbox_b = (const float*)d_in[4];
  const float* cls_w  = (const float*)d_in[5];
  const float* cls_b  = (const float*)d_in[6];
  const float* ang_w  = (const float*)d_in[7];
  const float* ang_b  = (const float*)d_in[8];
  float* out = (float*)d_out;
  float* ws = (float*)d_ws;

  float* partial = ws;            // 256
  float* boxes5  = ws + 320;      // 6000
  float* scores  = ws + 6320;     // 2400
  float* sparams = ws + 8720;     // 4*7*640 = 17920
  int*   order_g = (int*)(ws + 26640);                       // 4*640
  unsigned long long* mask = (unsigned long long*)(ws + 29200);  // 4*600*10 u64

  k_conv_pool<<<256, 256, 0, stream>>>(x, conv_w, conv_b, partial);
  k_heads<<<5, 256, 0, stream>>>(partial, bbox_w, bbox_b, cls_w, cls_b,
                                 ang_w, ang_b, boxes5, scores);
  k_prep<<<4, 256, 0, stream>>>(boxes5, scores, sparams, order_g);
  k_mask<<<600, 256, 0, stream>>>(sparams, order_g, mask);
  k_scan<<<4, 256, 0, stream>>>(boxes5, sparams, order_g, mask, out);
}

// Round 6
// 83.700 us; speedup vs baseline: 8.5867x; 1.2283x over previous
//
#include <hip/hip_runtime.h>
#include <hip/hip_bf16.h>

#define MAX_DET 300
#define NCAND 600           // MAX_DET * NUM_CLASSES
#define NPAD 640            // padded candidate stride
#define SCORE_THR 1e-3f
#define IOU_THR 0.7f
#define EPSF 1e-7f

// ws layout (floats):
//   [0, 256)         partial conv sums (4b * 16oc * 4chunks)
//   [320, 6320)      boxes5 (4*300*5)
//   [8720, 26640)    sorted params: 4 batches x 7 arrays x 640  (x,y,A,B,C,D,s)
//   [26640, 29200)   order (int), 4 x 640
//   [29200, 77200)   mask (u64), 4 x 600 x 10

static __device__ inline unsigned long long readlane64(unsigned long long v, int l) {
  unsigned int lo = (unsigned int)v;
  unsigned int hi = (unsigned int)(v >> 32);
  unsigned int slo = (unsigned int)__builtin_amdgcn_readlane((int)lo, l);
  unsigned int shi = (unsigned int)__builtin_amdgcn_readlane((int)hi, l);
  return ((unsigned long long)shi << 32) | (unsigned long long)slo;
}

__global__ __launch_bounds__(256) void k_conv_pool(
    const float* __restrict__ x, const float* __restrict__ cw,
    const float* __restrict__ cb, float* __restrict__ partial) {
  const int blk = blockIdx.x;  // (b*16 + oc)*4 + chunk
  const int chunk = blk & 3;
  const int oc = (blk >> 2) & 15;
  const int b = blk >> 6;
  const int tid = threadIdx.x;

  float w[27];
#pragma unroll
  for (int i = 0; i < 27; ++i) w[i] = cw[oc * 27 + i];
  const float bias = cb[oc];
  const float* xb = x + b * 3 * 65536;

  float acc = 0.f;
  for (int p = chunk * 4096 + tid; p < (chunk + 1) * 4096; p += 256) {
    const int py = p >> 7, px = p & 127;
    const int oy0 = py * 2, ox0 = px * 2;
    float c0 = 0.f, c1 = 0.f, c2 = 0.f, c3 = 0.f;
#pragma unroll
    for (int ic = 0; ic < 3; ++ic) {
      const float* xc = xb + ic * 65536;
      float vin[4][4];
#pragma unroll
      for (int r = 0; r < 4; ++r) {
        const int yy = oy0 - 1 + r;
#pragma unroll
        for (int c = 0; c < 4; ++c) {
          const int xx = ox0 - 1 + c;
          float v = 0.f;
          if (yy >= 0 && yy < 256 && xx >= 0 && xx < 256) v = xc[yy * 256 + xx];
          vin[r][c] = v;
        }
      }
#pragma unroll
      for (int ky = 0; ky < 3; ++ky)
#pragma unroll
        for (int kx = 0; kx < 3; ++kx) {
          const float wv = w[ic * 9 + ky * 3 + kx];
          c0 += vin[ky][kx] * wv;
          c1 += vin[ky][kx + 1] * wv;
          c2 += vin[ky + 1][kx] * wv;
          c3 += vin[ky + 1][kx + 1] * wv;
        }
    }
    const float m = fmaxf(fmaxf(c0, c1), fmaxf(c2, c3));
    acc += fmaxf(m + bias, 0.f);
  }
  __shared__ float red[256];
  red[tid] = acc;
  __syncthreads();
  for (int s = 128; s > 0; s >>= 1) {
    if (tid < s) red[tid] += red[tid + s];
    __syncthreads();
  }
  if (tid == 0) partial[blk] = red[0];
}

// Fused heads + stable-descending rank sort + sorted gaussian params.
// One block per batch.
__global__ __launch_bounds__(256) void k_prep(
    const float* __restrict__ partial,
    const float* __restrict__ bw, const float* __restrict__ bb,
    const float* __restrict__ cwm, const float* __restrict__ cbb,
    const float* __restrict__ aw, const float* __restrict__ ab,
    float* __restrict__ boxes5, float* __restrict__ sparams,
    int* __restrict__ order_g) {
  const int b = blockIdx.x;
  const int tid = threadIdx.x;
  const int wid = tid >> 6, lane = tid & 63;

  __shared__ float fm[16];
  __shared__ float sc[NPAD];
  __shared__ float sbox[MAX_DET * 5];
  __shared__ int order[NCAND];

  if (tid < 16) {
    float s = 0.f;
    for (int k = 0; k < 4; ++k) s += partial[(b * 16 + tid) * 4 + k];
    fm[tid] = s * (1.0f / 16384.0f);
  }
  // pad scores so rank ballots over word 9 are harmless
  for (int m = NCAND + tid; m < NPAD; m += 256) sc[m] = -1e30f;
  __syncthreads();

  float f[16];
#pragma unroll
  for (int k = 0; k < 16; ++k) f[k] = fm[k];

  // --- heads (300 dets, this batch) ---
  for (int det = tid; det < MAX_DET; det += 256) {
    float out5[5];
#pragma unroll
    for (int j = 0; j < 4; ++j) {
      const int o = det * 4 + j;
      float acc = bb[o];
#pragma unroll
      for (int k = 0; k < 16; ++k) acc += bw[o * 16 + k] * f[k];
      out5[j] = acc;
    }
    {
      float acc = ab[det];
#pragma unroll
      for (int k = 0; k < 16; ++k) acc += aw[det * 16 + k] * f[k];
      out5[4] = acc;
    }
    float l0, l1;
    {
      const int o = det * 2;
      float a0 = cbb[o], a1 = cbb[o + 1];
#pragma unroll
      for (int k = 0; k < 16; ++k) {
        a0 += cwm[o * 16 + k] * f[k];
        a1 += cwm[(o + 1) * 16 + k] * f[k];
      }
      l0 = a0; l1 = a1;
    }
    const float mx = fmaxf(l0, l1);
    const float e0 = expf(l0 - mx), e1 = expf(l1 - mx);
    const float inv = 1.f / (e0 + e1);

#pragma unroll
    for (int j = 0; j < 5; ++j) {
      sbox[det * 5 + j] = out5[j];
      boxes5[(b * MAX_DET + det) * 5 + j] = out5[j];
    }
    sc[det * 2 + 0] = e0 * inv;
    sc[det * 2 + 1] = e1 * inv;
  }
  __syncthreads();

  // --- rank sort: scores in registers, ballot-popcount rank ---
  float sreg[10];
#pragma unroll
  for (int k = 0; k < 10; ++k) sreg[k] = sc[k * 64 + lane];

#pragma unroll
  for (int w = 0; w < 10; ++w) {
#pragma unroll
    for (int t = 0; t < 16; ++t) {
      const int i = w * 64 + wid + 4 * t;   // wave-uniform
      if (i < NCAND) {
        float si;
        switch (w) {  // compile-time reg index for the broadcast source
          case 0: si = __shfl(sreg[0], i & 63); break;
          case 1: si = __shfl(sreg[1], i & 63); break;
          case 2: si = __shfl(sreg[2], i & 63); break;
          case 3: si = __shfl(sreg[3], i & 63); break;
          case 4: si = __shfl(sreg[4], i & 63); break;
          case 5: si = __shfl(sreg[5], i & 63); break;
          case 6: si = __shfl(sreg[6], i & 63); break;
          case 7: si = __shfl(sreg[7], i & 63); break;
          case 8: si = __shfl(sreg[8], i & 63); break;
          default: si = __shfl(sreg[9], i & 63); break;
        }
        int r = 0;
#pragma unroll
        for (int k = 0; k < 10; ++k) {
          const int j = k * 64 + lane;
          const bool c = (sreg[k] > si) || (sreg[k] == si && j < i);
          r += (int)__popcll(__ballot(c));
        }
        if (lane == 0) order[r] = i;
      }
    }
  }
  __syncthreads();

  // --- sorted gaussian params ---
  float* P = sparams + b * 7 * NPAD;
  for (int r = tid; r < NCAND; r += 256) {
    const int i = order[r];
    order_g[b * NPAD + r] = i;
    const float* bp = sbox + (i >> 1) * 5;
    const float cx = bp[0], cy = bp[1], w = bp[2], h = bp[3], t = bp[4];
    const float ct = cosf(t), st = sinf(t);
    const float w2 = w * w * (1.f / 12.f), h2 = h * h * (1.f / 12.f);
    const float a = w2 * ct * ct + h2 * st * st;
    const float bb2 = w2 * st * st + h2 * ct * ct;
    const float c = (w2 - h2) * ct * st;
    P[0 * NPAD + r] = cx;
    P[1 * NPAD + r] = cy;
    P[2 * NPAD + r] = a;
    P[3 * NPAD + r] = bb2;
    P[4 * NPAD + r] = c;
    P[5 * NPAD + r] = fmaxf(a * bb2 - c * c, 0.f);
    P[6 * NPAD + r] = sc[i];
  }
}

// One wave per sorted row; 10 ballots build the 600-bit suppression row.
__global__ __launch_bounds__(256) void k_mask(
    const float* __restrict__ sparams, const int* __restrict__ order_g,
    unsigned long long* __restrict__ mask) {
  const int wid = threadIdx.x >> 6, lane = threadIdx.x & 63;
  const int g = blockIdx.x * 4 + wid;  // 0 .. 2399
  const int b = g / NCAND, i = g % NCAND;

  const float* P = sparams + b * 7 * NPAD;
  const int* og = order_g + b * NPAD;
  const float x1 = P[i], y1 = P[NPAD + i], a1 = P[2 * NPAD + i],
              b1 = P[3 * NPAD + i], c1 = P[4 * NPAD + i], d1 = P[5 * NPAD + i];
  const int li = og[i] & 1;

#pragma unroll
  for (int w = 0; w < 10; ++w) {
    const int j = w * 64 + lane;
    const int jc = j < NCAND ? j : NCAND - 1;
    const float x2 = P[jc], y2 = P[NPAD + jc], a2 = P[2 * NPAD + jc],
                b2 = P[3 * NPAD + jc], c2 = P[4 * NPAD + jc],
                d2 = P[5 * NPAD + jc];
    const float as = a1 + a2, bs = b1 + b2, cs = c1 + c2;
    const float dxx = x2 - x1, dyy = y1 - y2;
    const float denom = as * bs - cs * cs + EPSF;
    const float rden = 1.f / denom;
    const float t1v = 0.25f * (as * dyy * dyy + bs * dxx * dxx) * rden;
    const float t2v = 0.5f * (cs * dxx * dyy) * rden;
    const float t3v = 0.5f * logf(denom / (4.f * sqrtf(d1 * d2) + EPSF) + EPSF);
    float bd = t1v + t2v + t3v;
    bd = fminf(fmaxf(bd, EPSF), 100.f);
    const float hd = sqrtf(1.f - expf(-bd) + EPSF);
    const bool cond = (j > i) && (j < NCAND) && ((og[jc] & 1) == li) &&
                      ((1.f - hd) > IOU_THR);
    const unsigned long long mw = __ballot(cond);
    if (lane == 0) mask[(b * NCAND + i) * 10 + w] = mw;
  }
}

// Scalar greedy scan over nonzero-mask rows only + output scatter. 256 threads.
__global__ __launch_bounds__(256) void k_scan(
    const float* __restrict__ boxes5, const float* __restrict__ sparams,
    const int* __restrict__ order_g, const unsigned long long* __restrict__ mask,
    float* __restrict__ out) {
  const int b = blockIdx.x;
  const int tid = threadIdx.x;
  const int wid = tid >> 6, lane = tid & 63;

  __shared__ unsigned long long m[NCAND * 10];
  __shared__ float ssc[NCAND];
  __shared__ unsigned long long keepw[10];
  __shared__ unsigned long long validbm[10];
  __shared__ unsigned long long nzbm[10];

  // coalesced global -> LDS mask copy (256 threads)
  const unsigned long long* mg = mask + b * NCAND * 10;
  for (int k = tid; k < NCAND * 10; k += 256) m[k] = mg[k];
  const float* P = sparams + b * 7 * NPAD;
  for (int k = tid; k < NCAND; k += 256) ssc[k] = P[6 * NPAD + k];
  __syncthreads();

  // ballot-built bitmaps: valid (score>thr) and nonzero-mask rows
#pragma unroll
  for (int it = 0; it < 3; ++it) {
    const int g = wid + 4 * it;  // word index 0..11
    if (g < 10) {
      const int r = g * 64 + lane;
      bool valid = false;
      unsigned long long nzr = 0ULL;
      if (r < NCAND) {
        valid = ssc[r] > SCORE_THR;
        for (int k = 0; k < 10; ++k) nzr |= m[r * 10 + k];
      }
      const unsigned long long vb = __ballot(valid);
      const unsigned long long nb = __ballot(nzr != 0ULL);
      if (lane == 0) { validbm[g] = vb; nzbm[g] = nb; }
    }
  }
  __syncthreads();

  // wave-0 scalar greedy scan: visit only rows with nonzero suppression mask
  if (tid < 64) {
    unsigned long long keep = (lane < 10) ? validbm[lane] : 0ULL;
    const unsigned long long nzv = (lane < 10) ? nzbm[lane] : 0ULL;
#pragma unroll
    for (int w = 0; w < 10; ++w) {
      unsigned long long nzs = readlane64(nzv, w);
      unsigned long long ks = readlane64(keep, w);  // scalar cache of keep word w
      while (nzs) {
        const int bit = __builtin_ctzll(nzs);
        nzs &= nzs - 1ULL;
        if ((ks >> bit) & 1ULL) {
          const int i = w * 64 + bit;
          unsigned long long row = 0ULL;
          if (lane < 10) row = m[i * 10 + lane];
          keep &= ~row;
          ks &= ~readlane64(row, w);
        }
      }
    }
    if (lane < 10) keepw[lane] = keep;
  }
  __syncthreads();

  for (int k = tid; k < MAX_DET * 5; k += 256) out[b * MAX_DET * 5 + k] = 0.f;
  for (int k = tid; k < MAX_DET; k += 256) {
    out[6000 + b * MAX_DET + k] = 0.f;   // scores
    out[7200 + b * MAX_DET + k] = 0.f;   // labels
  }
  __syncthreads();

  const int* og = order_g + b * NPAD;
  for (int r = tid; r < NCAND; r += 256) {
    const int w = r >> 6, bitp = r & 63;
    if ((keepw[w] >> bitp) & 1ULL) {
      int pos = 0;
      for (int ww = 0; ww < w; ++ww) pos += __popcll(keepw[ww]);
      pos += __popcll(keepw[w] & ((1ULL << bitp) - 1ULL));
      if (pos < MAX_DET) {
        const int i = og[r];
        const float* bp = boxes5 + (b * MAX_DET + (i >> 1)) * 5;
        float* ob = out + (b * MAX_DET + pos) * 5;
        ob[0] = bp[0]; ob[1] = bp[1]; ob[2] = bp[2]; ob[3] = bp[3]; ob[4] = bp[4];
        out[6000 + b * MAX_DET + pos] = ssc[r];
        out[7200 + b * MAX_DET + pos] = (float)(i & 1);
      }
    }
  }
  if (tid == 0) {
    int total = 0;
    for (int ww = 0; ww < 10; ++ww) total += __popcll(keepw[ww]);
    if (total > MAX_DET) total = MAX_DET;
    out[8400 + b] = (float)total;
  }
}

extern "C" void kernel_launch(void* const* d_in, const int* in_sizes, int n_in,
                              void* d_out, int out_size, void* d_ws, size_t ws_size,
                              hipStream_t stream) {
  const float* x      = (const float*)d_in[0];
  const float* conv_w = (const float*)d_in[1];
  const float* conv_b = (const float*)d_in[2];
  const float* bbox_w = (const float*)d_in[3];
  const float* bbox_b = (const float*)d_in[4];
  const float* cls_w  = (const float*)d_in[5];
  const float* cls_b  = (const float*)d_in[6];
  const float* ang_w  = (const float*)d_in[7];
  const float* ang_b  = (const float*)d_in[8];
  float* out = (float*)d_out;
  float* ws = (float*)d_ws;

  float* partial = ws;            // 256
  float* boxes5  = ws + 320;      // 6000
  float* sparams = ws + 8720;     // 4*7*640 = 17920
  int*   order_g = (int*)(ws + 26640);                       // 4*640
  unsigned long long* mask = (unsigned long long*)(ws + 29200);  // 4*600*10 u64

  k_conv_pool<<<256, 256, 0, stream>>>(x, conv_w, conv_b, partial);
  k_prep<<<4, 256, 0, stream>>>(partial, bbox_w, bbox_b, cls_w, cls_b,
                                ang_w, ang_b, boxes5, sparams, order_g);
  k_mask<<<600, 256, 0, stream>>>(sparams, order_g, mask);
  k_scan<<<4, 256, 0, stream>>>(boxes5, sparams, order_g, mask, out);
}

// Round 7
// 66.205 us; speedup vs baseline: 10.8558x; 1.2643x over previous
//
#include <hip/hip_runtime.h>
#include <hip/hip_bf16.h>

#define MAX_DET 300
#define NCAND 600           // MAX_DET * NUM_CLASSES
#define NPAD 640            // padded candidate stride
#define SCORE_THR 1e-3f
#define IOU_THR 0.7f
#define EPSF 1e-7f

typedef float float4u __attribute__((ext_vector_type(4), aligned(4)));

// ws layout (floats):
//   [0, 512)         partial conv sums (4b * 16oc * 8chunks)
//   [1024, 7024)     boxes5 (4*300*5)
//   [8720, 26640)    sorted params: 4 batches x 7 arrays x 640  (x,y,A,B,C,D,s)
//   [26640, 29200)   order (int), 4 x 640
//   [29200, 77200)   mask (u64), 4 x 600 x 10

static __device__ inline unsigned long long readlane64(unsigned long long v, int l) {
  unsigned int lo = (unsigned int)v;
  unsigned int hi = (unsigned int)(v >> 32);
  unsigned int slo = (unsigned int)__builtin_amdgcn_readlane((int)lo, l);
  unsigned int shi = (unsigned int)__builtin_amdgcn_readlane((int)hi, l);
  return ((unsigned long long)shi << 32) | (unsigned long long)slo;
}

// 512 blocks: blk = (b*16 + oc)*8 + chunk. Each thread: one 8-px pooled strip.
__global__ __launch_bounds__(256) void k_conv_pool(
    const float* __restrict__ x, const float* __restrict__ cw,
    const float* __restrict__ cb, float* __restrict__ partial) {
  const int blk = blockIdx.x;
  const int chunk = blk & 7;
  const int oc = (blk >> 3) & 15;
  const int b = blk >> 7;
  const int tid = threadIdx.x;

  float w[27];
#pragma unroll
  for (int i = 0; i < 27; ++i) w[i] = cw[oc * 27 + i];
  const float bias = cb[oc];
  const float* xb = x + b * 3 * 65536;

  const int strip = chunk * 256 + tid;   // 0..2047
  const int py = strip >> 4;             // pooled row 0..127
  const int x0 = (strip & 15) * 8;       // pooled col start: 0,8,...,120

  // per-px conv accumulators: cc0=c(2py,2px), cc1=c(2py,2px+1),
  //                           cc2=c(2py+1,2px), cc3=c(2py+1,2px+1)
  float cc0[8], cc1[8], cc2[8], cc3[8];
#pragma unroll
  for (int i = 0; i < 8; ++i) { cc0[i] = 0.f; cc1[i] = 0.f; cc2[i] = 0.f; cc3[i] = 0.f; }

#pragma unroll
  for (int ic = 0; ic < 3; ++ic) {
    const float* xc = xb + ic * 65536;
    const float* wc = w + ic * 9;
#pragma unroll
    for (int r = 0; r < 4; ++r) {
      const int y = 2 * py - 1 + r;
      if (y < 0 || y > 255) continue;
      const float* xr = xc + y * 256;
      float buf[20];
#pragma unroll
      for (int k = 0; k < 5; ++k) {
        const int c0 = 2 * x0 - 1 + 4 * k;
        if (c0 >= 0 && c0 + 3 <= 255) {
          const float4u v = *reinterpret_cast<const float4u*>(xr + c0);
          buf[4 * k + 0] = v.x; buf[4 * k + 1] = v.y;
          buf[4 * k + 2] = v.z; buf[4 * k + 3] = v.w;
        } else {
#pragma unroll
          for (int j = 0; j < 4; ++j) {
            const int c = c0 + j;
            buf[4 * k + j] = (c >= 0 && c <= 255) ? xr[c] : 0.f;
          }
        }
      }
#pragma unroll
      for (int i = 0; i < 8; ++i) {
        const float b0 = buf[2 * i], b1 = buf[2 * i + 1],
                    b2 = buf[2 * i + 2], b3 = buf[2 * i + 3];
        if (r <= 2) {  // top conv rows (output row 2py), kernel row r
          const float w0 = wc[r * 3], w1 = wc[r * 3 + 1], w2 = wc[r * 3 + 2];
          cc0[i] += b0 * w0 + b1 * w1 + b2 * w2;
          cc1[i] += b1 * w0 + b2 * w1 + b3 * w2;
        }
        if (r >= 1) {  // bottom conv rows (output row 2py+1), kernel row r-1
          const float w0 = wc[(r - 1) * 3], w1 = wc[(r - 1) * 3 + 1],
                      w2 = wc[(r - 1) * 3 + 2];
          cc2[i] += b0 * w0 + b1 * w1 + b2 * w2;
          cc3[i] += b1 * w0 + b2 * w1 + b3 * w2;
        }
      }
    }
  }

  float acc = 0.f;
#pragma unroll
  for (int i = 0; i < 8; ++i) {
    const float m = fmaxf(fmaxf(cc0[i], cc1[i]), fmaxf(cc2[i], cc3[i]));
    acc += fmaxf(m + bias, 0.f);
  }

  __shared__ float red[256];
  red[tid] = acc;
  __syncthreads();
  for (int s = 128; s > 0; s >>= 1) {
    if (tid < s) red[tid] += red[tid + s];
    __syncthreads();
  }
  if (tid == 0) partial[blk] = red[0];
}

// Fused heads + stable-descending rank sort + sorted gaussian params.
// One block per batch.
__global__ __launch_bounds__(256) void k_prep(
    const float* __restrict__ partial,
    const float* __restrict__ bw, const float* __restrict__ bb,
    const float* __restrict__ cwm, const float* __restrict__ cbb,
    const float* __restrict__ aw, const float* __restrict__ ab,
    float* __restrict__ boxes5, float* __restrict__ sparams,
    int* __restrict__ order_g) {
  const int b = blockIdx.x;
  const int tid = threadIdx.x;
  const int wid = tid >> 6, lane = tid & 63;

  __shared__ float fm[16];
  __shared__ float sc[NPAD];
  __shared__ float sbox[MAX_DET * 5];
  __shared__ int order[NCAND];

  if (tid < 16) {
    float s = 0.f;
    for (int k = 0; k < 8; ++k) s += partial[(b * 16 + tid) * 8 + k];
    fm[tid] = s * (1.0f / 16384.0f);
  }
  // pad scores so rank ballots over word 9 are harmless
  for (int m = NCAND + tid; m < NPAD; m += 256) sc[m] = -1e30f;
  __syncthreads();

  float f[16];
#pragma unroll
  for (int k = 0; k < 16; ++k) f[k] = fm[k];

  // --- heads (300 dets, this batch) ---
  for (int det = tid; det < MAX_DET; det += 256) {
    float out5[5];
#pragma unroll
    for (int j = 0; j < 4; ++j) {
      const int o = det * 4 + j;
      float acc = bb[o];
#pragma unroll
      for (int k = 0; k < 16; ++k) acc += bw[o * 16 + k] * f[k];
      out5[j] = acc;
    }
    {
      float acc = ab[det];
#pragma unroll
      for (int k = 0; k < 16; ++k) acc += aw[det * 16 + k] * f[k];
      out5[4] = acc;
    }
    float l0, l1;
    {
      const int o = det * 2;
      float a0 = cbb[o], a1 = cbb[o + 1];
#pragma unroll
      for (int k = 0; k < 16; ++k) {
        a0 += cwm[o * 16 + k] * f[k];
        a1 += cwm[(o + 1) * 16 + k] * f[k];
      }
      l0 = a0; l1 = a1;
    }
    const float mx = fmaxf(l0, l1);
    const float e0 = expf(l0 - mx), e1 = expf(l1 - mx);
    const float inv = 1.f / (e0 + e1);

#pragma unroll
    for (int j = 0; j < 5; ++j) {
      sbox[det * 5 + j] = out5[j];
      boxes5[(b * MAX_DET + det) * 5 + j] = out5[j];
    }
    sc[det * 2 + 0] = e0 * inv;
    sc[det * 2 + 1] = e1 * inv;
  }
  __syncthreads();

  // --- rank sort: scores in registers, ballot-popcount rank ---
  float sreg[10];
#pragma unroll
  for (int k = 0; k < 10; ++k) sreg[k] = sc[k * 64 + lane];

#pragma unroll
  for (int w = 0; w < 10; ++w) {
#pragma unroll
    for (int t = 0; t < 16; ++t) {
      const int i = w * 64 + wid + 4 * t;   // wave-uniform
      if (i < NCAND) {
        float si;
        switch (w) {  // compile-time reg index for the broadcast source
          case 0: si = __shfl(sreg[0], i & 63); break;
          case 1: si = __shfl(sreg[1], i & 63); break;
          case 2: si = __shfl(sreg[2], i & 63); break;
          case 3: si = __shfl(sreg[3], i & 63); break;
          case 4: si = __shfl(sreg[4], i & 63); break;
          case 5: si = __shfl(sreg[5], i & 63); break;
          case 6: si = __shfl(sreg[6], i & 63); break;
          case 7: si = __shfl(sreg[7], i & 63); break;
          case 8: si = __shfl(sreg[8], i & 63); break;
          default: si = __shfl(sreg[9], i & 63); break;
        }
        int r = 0;
#pragma unroll
        for (int k = 0; k < 10; ++k) {
          const int j = k * 64 + lane;
          const bool c = (sreg[k] > si) || (sreg[k] == si && j < i);
          r += (int)__popcll(__ballot(c));
        }
        if (lane == 0) order[r] = i;
      }
    }
  }
  __syncthreads();

  // --- sorted gaussian params ---
  float* P = sparams + b * 7 * NPAD;
  for (int r = tid; r < NCAND; r += 256) {
    const int i = order[r];
    order_g[b * NPAD + r] = i;
    const float* bp = sbox + (i >> 1) * 5;
    const float cx = bp[0], cy = bp[1], w = bp[2], h = bp[3], t = bp[4];
    const float ct = cosf(t), st = sinf(t);
    const float w2 = w * w * (1.f / 12.f), h2 = h * h * (1.f / 12.f);
    const float a = w2 * ct * ct + h2 * st * st;
    const float bb2 = w2 * st * st + h2 * ct * ct;
    const float c = (w2 - h2) * ct * st;
    P[0 * NPAD + r] = cx;
    P[1 * NPAD + r] = cy;
    P[2 * NPAD + r] = a;
    P[3 * NPAD + r] = bb2;
    P[4 * NPAD + r] = c;
    P[5 * NPAD + r] = fmaxf(a * bb2 - c * c, 0.f);
    P[6 * NPAD + r] = sc[i];
  }
}

// One wave per sorted row; 10 ballots build the 600-bit suppression row.
__global__ __launch_bounds__(256) void k_mask(
    const float* __restrict__ sparams, const int* __restrict__ order_g,
    unsigned long long* __restrict__ mask) {
  const int wid = threadIdx.x >> 6, lane = threadIdx.x & 63;
  const int g = blockIdx.x * 4 + wid;  // 0 .. 2399
  const int b = g / NCAND, i = g % NCAND;

  const float* P = sparams + b * 7 * NPAD;
  const int* og = order_g + b * NPAD;
  const float x1 = P[i], y1 = P[NPAD + i], a1 = P[2 * NPAD + i],
              b1 = P[3 * NPAD + i], c1 = P[4 * NPAD + i], d1 = P[5 * NPAD + i];
  const int li = og[i] & 1;

#pragma unroll
  for (int w = 0; w < 10; ++w) {
    const int j = w * 64 + lane;
    const int jc = j < NCAND ? j : NCAND - 1;
    const float x2 = P[jc], y2 = P[NPAD + jc], a2 = P[2 * NPAD + jc],
                b2 = P[3 * NPAD + jc], c2 = P[4 * NPAD + jc],
                d2 = P[5 * NPAD + jc];
    const float as = a1 + a2, bs = b1 + b2, cs = c1 + c2;
    const float dxx = x2 - x1, dyy = y1 - y2;
    const float denom = as * bs - cs * cs + EPSF;
    const float rden = 1.f / denom;
    const float t1v = 0.25f * (as * dyy * dyy + bs * dxx * dxx) * rden;
    const float t2v = 0.5f * (cs * dxx * dyy) * rden;
    const float t3v = 0.5f * logf(denom / (4.f * sqrtf(d1 * d2) + EPSF) + EPSF);
    float bd = t1v + t2v + t3v;
    bd = fminf(fmaxf(bd, EPSF), 100.f);
    const float hd = sqrtf(1.f - expf(-bd) + EPSF);
    const bool cond = (j > i) && (j < NCAND) && ((og[jc] & 1) == li) &&
                      ((1.f - hd) > IOU_THR);
    const unsigned long long mw = __ballot(cond);
    if (lane == 0) mask[(b * NCAND + i) * 10 + w] = mw;
  }
}

// Scalar greedy scan over nonzero-mask rows only + output scatter. 256 threads.
__global__ __launch_bounds__(256) void k_scan(
    const float* __restrict__ boxes5, const float* __restrict__ sparams,
    const int* __restrict__ order_g, const unsigned long long* __restrict__ mask,
    float* __restrict__ out) {
  const int b = blockIdx.x;
  const int tid = threadIdx.x;
  const int wid = tid >> 6, lane = tid & 63;

  __shared__ unsigned long long m[NCAND * 10];
  __shared__ float ssc[NCAND];
  __shared__ unsigned long long keepw[10];
  __shared__ unsigned long long validbm[10];
  __shared__ unsigned long long nzbm[10];

  // coalesced global -> LDS mask copy (256 threads)
  const unsigned long long* mg = mask + b * NCAND * 10;
  for (int k = tid; k < NCAND * 10; k += 256) m[k] = mg[k];
  const float* P = sparams + b * 7 * NPAD;
  for (int k = tid; k < NCAND; k += 256) ssc[k] = P[6 * NPAD + k];
  __syncthreads();

  // ballot-built bitmaps: valid (score>thr) and nonzero-mask rows
#pragma unroll
  for (int it = 0; it < 3; ++it) {
    const int g = wid + 4 * it;  // word index 0..11
    if (g < 10) {
      const int r = g * 64 + lane;
      bool valid = false;
      unsigned long long nzr = 0ULL;
      if (r < NCAND) {
        valid = ssc[r] > SCORE_THR;
        for (int k = 0; k < 10; ++k) nzr |= m[r * 10 + k];
      }
      const unsigned long long vb = __ballot(valid);
      const unsigned long long nb = __ballot(nzr != 0ULL);
      if (lane == 0) { validbm[g] = vb; nzbm[g] = nb; }
    }
  }
  __syncthreads();

  // wave-0 scalar greedy scan: visit only rows with nonzero suppression mask
  if (tid < 64) {
    unsigned long long keep = (lane < 10) ? validbm[lane] : 0ULL;
    const unsigned long long nzv = (lane < 10) ? nzbm[lane] : 0ULL;
#pragma unroll
    for (int w = 0; w < 10; ++w) {
      unsigned long long nzs = readlane64(nzv, w);
      unsigned long long ks = readlane64(keep, w);  // scalar cache of keep word w
      while (nzs) {
        const int bit = __builtin_ctzll(nzs);
        nzs &= nzs - 1ULL;
        if ((ks >> bit) & 1ULL) {
          const int i = w * 64 + bit;
          unsigned long long row = 0ULL;
          if (lane < 10) row = m[i * 10 + lane];
          keep &= ~row;
          ks &= ~readlane64(row, w);
        }
      }
    }
    if (lane < 10) keepw[lane] = keep;
  }
  __syncthreads();

  for (int k = tid; k < MAX_DET * 5; k += 256) out[b * MAX_DET * 5 + k] = 0.f;
  for (int k = tid; k < MAX_DET; k += 256) {
    out[6000 + b * MAX_DET + k] = 0.f;   // scores
    out[7200 + b * MAX_DET + k] = 0.f;   // labels
  }
  __syncthreads();

  const int* og = order_g + b * NPAD;
  for (int r = tid; r < NCAND; r += 256) {
    const int w = r >> 6, bitp = r & 63;
    if ((keepw[w] >> bitp) & 1ULL) {
      int pos = 0;
      for (int ww = 0; ww < w; ++ww) pos += __popcll(keepw[ww]);
      pos += __popcll(keepw[w] & ((1ULL << bitp) - 1ULL));
      if (pos < MAX_DET) {
        const int i = og[r];
        const float* bp = boxes5 + (b * MAX_DET + (i >> 1)) * 5;
        float* ob = out + (b * MAX_DET + pos) * 5;
        ob[0] = bp[0]; ob[1] = bp[1]; ob[2] = bp[2]; ob[3] = bp[3]; ob[4] = bp[4];
        out[6000 + b * MAX_DET + pos] = ssc[r];
        out[7200 + b * MAX_DET + pos] = (float)(i & 1);
      }
    }
  }
  if (tid == 0) {
    int total = 0;
    for (int ww = 0; ww < 10; ++ww) total += __popcll(keepw[ww]);
    if (total > MAX_DET) total = MAX_DET;
    out[8400 + b] = (float)total;
  }
}

extern "C" void kernel_launch(void* const* d_in, const int* in_sizes, int n_in,
                              void* d_out, int out_size, void* d_ws, size_t ws_size,
                              hipStream_t stream) {
  const float* x      = (const float*)d_in[0];
  const float* conv_w = (const float*)d_in[1];
  const float* conv_b = (const float*)d_in[2];
  const float* bbox_w = (const float*)d_in[3];
  const float* bbox_b = (const float*)d_in[4];
  const float* cls_w  = (const float*)d_in[5];
  const float* cls_b  = (const float*)d_in[6];
  const float* ang_w  = (const float*)d_in[7];
  const float* ang_b  = (const float*)d_in[8];
  float* out = (float*)d_out;
  float* ws = (float*)d_ws;

  float* partial = ws;            // 512
  float* boxes5  = ws + 1024;     // 6000
  float* sparams = ws + 8720;     // 4*7*640 = 17920
  int*   order_g = (int*)(ws + 26640);                       // 4*640
  unsigned long long* mask = (unsigned long long*)(ws + 29200);  // 4*600*10 u64

  k_conv_pool<<<512, 256, 0, stream>>>(x, conv_w, conv_b, partial);
  k_prep<<<4, 256, 0, stream>>>(partial, bbox_w, bbox_b, cls_w, cls_b,
                                ang_w, ang_b, boxes5, sparams, order_g);
  k_mask<<<600, 256, 0, stream>>>(sparams, order_g, mask);
  k_scan<<<4, 256, 0, stream>>>(boxes5, sparams, order_g, mask, out);
}